// Round 1
// baseline (118.506 us; speedup 1.0000x reference)
//
#include <hip/hip_runtime.h>

// LandmarkLoss: B=4 batches, N=200000 points, K=64 targets, classes={0..5}.
// Strategy: one wave owns 64*P points per chunk; targets live in LDS with
// invalid targets set to a -1e18 sentinel (distances ~1e36 emulate jnp.inf
// masking). Per iteration i, lane l processes target (l+i)&63 so that the
// per-target g2p min can be delivered to its home lane with ONE __shfl
// (ds_bpermute) instead of a full wave reduction.

constexpr int KT = 64;          // targets per batch (fixed)
constexpr int P  = 2;           // points per thread per chunk
constexpr float DIST_THRESH = 0.1f;
constexpr float W_DIST    = 0.05f;
constexpr float W_CHAMFER = 0.05f;
constexpr float W_SEP     = 0.0005f;
constexpr float PT_SENT = 1e18f;   // dummy-point sentinel (tail lanes)
constexpr float TG_SENT = -1e18f;  // invalid-target sentinel (opposite sign:
                                   // dummy-vs-invalid dist = (2e18)^2, no 0/0)
constexpr float BIGF = 3.0e38f;

__global__ void init_ws_kernel(unsigned int* g2p, float* sums, int ng, int ns) {
    int t = blockIdx.x * blockDim.x + threadIdx.x;
    if (t < ng) g2p[t] = 0x7F7FFFFFu;   // FLT_MAX bits (uint order == float order for +floats)
    if (t < ns) sums[t] = 0.0f;
}

__global__ __launch_bounds__(256, 2)
void landmark_main(const float* __restrict__ C, const float* __restrict__ F,
                   const float* __restrict__ tC, const int* __restrict__ tF,
                   const int* __restrict__ classes, int n_classes,
                   int B, int N, int blocks_per_batch, int chunks_per_batch,
                   unsigned int* __restrict__ g2p_ws, float* __restrict__ sums)
{
    __shared__ float tx[KT], ty[KT], tz[KT];
    __shared__ float gredw[4][KT];
    __shared__ float rs[3][4];

    const int tid  = threadIdx.x;
    const int lane = tid & 63;
    const int wib  = tid >> 6;                       // wave in block (0..3)
    const int b    = blockIdx.x / blocks_per_batch;  // batch of this block
    const int waves_per_batch = blocks_per_batch * (blockDim.x >> 6);
    const int wid  = (blockIdx.x - b * blocks_per_batch) * (blockDim.x >> 6) + wib;

    // Stage this batch's 64 targets into LDS, sentinel-ing invalid classes.
    if (tid < KT) {
        int f = tF[b * KT + tid];
        bool valid = false;
        for (int c = 0; c < n_classes; ++c) valid = valid || (f == classes[c]);
        float x = TG_SENT, y = TG_SENT, z = TG_SENT;
        if (valid) {
            x = tC[(b * KT + tid) * 3 + 0];
            y = tC[(b * KT + tid) * 3 + 1];
            z = tC[(b * KT + tid) * 3 + 2];
        }
        tx[tid] = x; ty[tid] = y; tz[tid] = z;
    }
    __syncthreads();

    const float*  Cb = C + (size_t)b * N * 3;
    const float4* Fb = (const float4*)(F + (size_t)b * N * 4);

    float gmin = BIGF;                      // g2p accumulator for target k == lane
    float dist_acc = 0.f, p2g_acc = 0.f, sep_acc = 0.f;

    for (int chunk = wid; chunk < chunks_per_batch; chunk += waves_per_batch) {
        const int base = chunk * (64 * P);

        float px[P], py[P], pz[P], cx[P], cy[P], cz[P], f0[P];
        bool  vp[P];
        #pragma unroll
        for (int p = 0; p < P; ++p) {
            int n = base + p * 64 + lane;
            bool v = (n < N);
            vp[p] = v;
            int ni = v ? n : 0;
            float4 f4 = Fb[ni];
            float X = Cb[3 * ni + 0], Y = Cb[3 * ni + 1], Z = Cb[3 * ni + 2];
            f0[p] = f4.x;
            if (v) {
                px[p] = X;           py[p] = Y;           pz[p] = Z;
                cx[p] = X + f4.y;    cy[p] = Y + f4.z;    cz[p] = Z + f4.w;
            } else {
                px[p] = PT_SENT; py[p] = PT_SENT; pz[p] = PT_SENT;
                cx[p] = PT_SENT; cy[p] = PT_SENT; cz[p] = PT_SENT;
            }
        }

        float m1[P], m2[P], l1[P], l2[P], lmin[P];
        #pragma unroll
        for (int p = 0; p < P; ++p) {
            m1[p] = BIGF; m2[p] = BIGF; l1[p] = BIGF; l2[p] = BIGF; lmin[p] = BIGF;
        }

        int kk = lane;
        #pragma unroll 8
        for (int i = 0; i < 64; ++i) {
            float Tx = tx[kk], Ty = ty[kk], Tz = tz[kk];
            float dl = BIGF;   // min ld2 over this thread's P points, for target kk
            #pragma unroll
            for (int p = 0; p < P; ++p) {
                float dx = px[p] - Tx, dy = py[p] - Ty, dz = pz[p] - Tz;
                float pd2 = fmaf(dz, dz, fmaf(dy, dy, dx * dx));
                float ex = cx[p] - Tx, ey = cy[p] - Ty, ez = cz[p] - Tz;
                float ld2 = fmaf(ez, ez, fmaf(ey, ey, ex * ex));
                // track (min, 2nd-min) of pd2 with companion ld2 values
                bool c1 = pd2 < m1[p];
                bool c2 = pd2 < m2[p];
                m2[p] = c1 ? m1[p] : (c2 ? pd2 : m2[p]);
                l2[p] = c1 ? l1[p] : (c2 ? ld2 : l2[p]);
                m1[p] = c1 ? pd2 : m1[p];
                l1[p] = c1 ? ld2 : l1[p];
                lmin[p] = fminf(lmin[p], ld2);
                dl = fminf(dl, ld2);
            }
            // deliver ld2 for target kk to its home lane (lane j reads from
            // the lane whose rotated target index equals j)
            float got = __shfl(dl, (lane - i) & 63, 64);
            gmin = fminf(gmin, got);
            kk = (kk + 1) & 63;
        }

        #pragma unroll
        for (int p = 0; p < P; ++p) {
            float mind = sqrtf(m1[p]);                 // inf-masked via sentinel
            bool pm = mind < DIST_THRESH;
            float tgt = fminf(mind, 2.0f * DIST_THRESH);  // clip(min_d,0,0.2); min_d>=0
            float diff = f0[p] - tgt;
            float ad = fabsf(diff);
            float sl1 = (ad < 1.0f) ? 0.5f * diff * diff : (ad - 0.5f);
            if (vp[p]) dist_acc += sl1;
            if (pm) {                                   // pm false for dummy points
                p2g_acc += lmin[p];                     // (sqrt(min ld2))^2 == min ld2
                sep_acc += sqrtf(l1[p]) / sqrtf(l2[p]);
            }
        }
    }

    // Block-reduce the three scalar sums (wave shuffle -> LDS -> atomics).
    float v0 = dist_acc, v1 = p2g_acc, v2 = sep_acc;
    #pragma unroll
    for (int o = 32; o > 0; o >>= 1) {
        v0 += __shfl_down(v0, o, 64);
        v1 += __shfl_down(v1, o, 64);
        v2 += __shfl_down(v2, o, 64);
    }
    if (lane == 0) { rs[0][wib] = v0; rs[1][wib] = v1; rs[2][wib] = v2; }
    gredw[wib][lane] = gmin;
    __syncthreads();

    const int nw = blockDim.x >> 6;
    if (tid < 3) {
        float s = 0.f;
        for (int w = 0; w < nw; ++w) s += rs[tid][w];
        atomicAdd(&sums[tid * B + b], s);
    }
    if (tid < KT) {
        float g = gredw[0][tid];
        for (int w = 1; w < nw; ++w) g = fminf(g, gredw[w][tid]);
        atomicMin(&g2p_ws[b * KT + tid], __float_as_uint(g));
    }
}

__global__ void landmark_finalize(const int* __restrict__ tF, const int* __restrict__ classes,
                                  int n_classes, const unsigned int* __restrict__ g2p_ws,
                                  const float* __restrict__ sums, float* __restrict__ out, int B)
{
    int tid = threadIdx.x;
    int b = tid >> 6, k = tid & 63;
    __shared__ float lossb[32];
    float g = 0.f, nv = 0.f;
    if (b < B) {
        int f = tF[b * KT + k];
        bool valid = false;
        for (int c = 0; c < n_classes; ++c) valid = valid || (f == classes[c]);
        if (valid) { nv = 1.f; g = __uint_as_float(g2p_ws[b * KT + k]); }
    }
    #pragma unroll
    for (int o = 32; o > 0; o >>= 1) {
        g  += __shfl_down(g, o, 64);
        nv += __shfl_down(nv, o, 64);
    }
    if (b < B && k == 0) {
        float sep = (nv >= 2.f) ? sums[2 * B + b] : 0.f;
        lossb[b] = W_DIST * sums[b] + W_CHAMFER * (sums[B + b] + g) + W_SEP * sep;
    }
    __syncthreads();
    if (tid == 0) {
        float s = 0.f;
        for (int i = 0; i < B; ++i) s += lossb[i];
        out[0] = s / (float)B;
    }
}

extern "C" void kernel_launch(void* const* d_in, const int* in_sizes, int n_in,
                              void* d_out, int out_size, void* d_ws, size_t ws_size,
                              hipStream_t stream)
{
    const float* C       = (const float*)d_in[0];   // (B,N,3)
    const float* F       = (const float*)d_in[1];   // (B,N,4)
    const float* tC      = (const float*)d_in[2];   // (B,K,3)
    const int*   tF      = (const int*)d_in[3];     // (B,K)
    const int*   classes = (const int*)d_in[4];     // (6,)
    const int n_classes = in_sizes[4];
    const int B = 4;
    const int N = in_sizes[0] / (3 * B);            // 200000

    unsigned int* g2p_ws = (unsigned int*)d_ws;
    float* sums = (float*)((char*)d_ws + (size_t)B * KT * sizeof(unsigned int));

    init_ws_kernel<<<1, 512, 0, stream>>>(g2p_ws, sums, B * KT, 3 * B);

    const int bpb = 128;                            // blocks per batch -> 512 blocks total
    const int cpb = (N + 64 * P - 1) / (64 * P);    // chunks per batch
    landmark_main<<<bpb * B, 256, 0, stream>>>(C, F, tC, tF, classes, n_classes,
                                               B, N, bpb, cpb, g2p_ws, sums);
    landmark_finalize<<<1, B * 64, 0, stream>>>(tF, classes, n_classes, g2p_ws, sums,
                                                (float*)d_out, B);
}

// Round 2
// 111.953 us; speedup vs baseline: 1.0585x; 1.0585x over previous
//
#include <hip/hip_runtime.h>

// LandmarkLoss fused single-kernel version.
// B=4, N=200000, K=64 targets, classes subset of {0..7}.
//
// Per wave: 256 points (P=4 per lane), rotated-k scheduling: at iteration i,
// lane l processes target (l+i)&63, so the per-target g2p min is delivered to
// its home lane with ONE __shfl (ds_bpermute). Targets stored in LDS as
// float4 (-2tx,-2ty,-2tz,|t|^2); distances via d2 = pp + tt - 2 p.t
// (dot form; |err|~1e-7 absolute, tolerance is 3.34 on the final scalar).
// Invalid targets get coord sentinel -1e18 (distances ~1e36+ emulate inf).
// Final reduction: ticket counter, last block reduces + writes out[0].

constexpr int KT = 64;
constexpr int P  = 4;
constexpr float DIST_THRESH = 0.1f;
constexpr float W_DIST    = 0.05f;
constexpr float W_CHAMFER = 0.05f;
constexpr float W_SEP     = 0.0005f;
constexpr float PT_SENT = 1e18f;   // dummy-point sentinel (tail lanes)
constexpr float TG_SENT = -1e18f;  // invalid-target sentinel
constexpr float BIGF = 3.0e38f;

__global__ __launch_bounds__(256, 4)
void landmark_fused(const float* __restrict__ C, const float* __restrict__ F,
                    const float* __restrict__ tC, const int* __restrict__ tF,
                    const int* __restrict__ classes, int n_classes,
                    int B, int N, int bpb, int cpb,
                    unsigned int* __restrict__ g2p_ws, float* __restrict__ sums,
                    unsigned int* __restrict__ ticket, float* __restrict__ out)
{
    __shared__ float4 tgt[KT];
    __shared__ float gredw[4][KT];
    __shared__ float rs[3][4];
    __shared__ int is_last;
    __shared__ float lossb[4];

    const int tid  = threadIdx.x;
    const int lane = tid & 63;
    const int wib  = tid >> 6;
    const int b    = blockIdx.x / bpb;
    const int waves_per_batch = bpb * 4;
    const int wid  = (blockIdx.x - b * bpb) * 4 + wib;

    // Stage this batch's 64 targets: (-2tx,-2ty,-2tz, |t|^2), sentinel if invalid.
    if (tid < KT) {
        int f = tF[b * KT + tid];
        bool valid = false;
        for (int c = 0; c < n_classes; ++c) valid = valid || (f == classes[c]);
        float x = TG_SENT, y = TG_SENT, z = TG_SENT;
        if (valid) {
            x = tC[(b * KT + tid) * 3 + 0];
            y = tC[(b * KT + tid) * 3 + 1];
            z = tC[(b * KT + tid) * 3 + 2];
        }
        tgt[tid] = make_float4(-2.f * x, -2.f * y, -2.f * z,
                               x * x + y * y + z * z);
    }
    __syncthreads();

    const float*  Cb = C + (size_t)b * N * 3;
    const float4* Fb = (const float4*)(F + (size_t)b * N * 4);

    float gmin = BIGF;                       // g2p min for target k == lane
    float dist_acc = 0.f, p2g_acc = 0.f, sep_acc = 0.f;

    for (int chunk = wid; chunk < cpb; chunk += waves_per_batch) {
        const int base = chunk * (64 * P);

        float px[P], py[P], pz[P], pp[P], cx[P], cy[P], cz[P], cc[P], f0[P];
        bool  vp[P];
        #pragma unroll
        for (int p = 0; p < P; ++p) {
            int n = base + p * 64 + lane;
            bool v = (n < N);
            vp[p] = v;
            int ni = v ? n : 0;
            float4 f4 = Fb[ni];
            float X = Cb[3 * ni + 0], Y = Cb[3 * ni + 1], Z = Cb[3 * ni + 2];
            f0[p] = f4.x;
            if (!v) { X = PT_SENT; Y = PT_SENT; Z = PT_SENT; f4.y = f4.z = f4.w = 0.f; }
            px[p] = X;          py[p] = Y;          pz[p] = Z;
            cx[p] = X + f4.y;   cy[p] = Y + f4.z;   cz[p] = Z + f4.w;
            pp[p] = fmaf(X, X, fmaf(Y, Y, Z * Z)) + fmaf(f4.y, f4.y, 0.f) * 0.f; // pp = |p|^2
            pp[p] = fmaf(pz[p], pz[p], fmaf(py[p], py[p], px[p] * px[p]));
            cc[p] = fmaf(cz[p], cz[p], fmaf(cy[p], cy[p], cx[p] * cx[p]));
        }

        float m1[P], m2[P], l1[P], l2[P], lmin[P];
        #pragma unroll
        for (int p = 0; p < P; ++p) {
            m1[p] = BIGF; m2[p] = BIGF; l1[p] = BIGF; l2[p] = BIGF; lmin[p] = BIGF;
        }

        int kk = lane;
        #pragma unroll 4
        for (int i = 0; i < 64; ++i) {
            float4 T = tgt[kk];
            float dl = BIGF;
            #pragma unroll
            for (int p = 0; p < P; ++p) {
                float pd2 = fmaf(px[p], T.x, fmaf(py[p], T.y, fmaf(pz[p], T.z, pp[p] + T.w)));
                float ld2 = fmaf(cx[p], T.x, fmaf(cy[p], T.y, fmaf(cz[p], T.z, cc[p] + T.w)));
                bool c1 = pd2 < m1[p];
                bool c2 = pd2 < m2[p];
                float hi = fmaxf(m1[p], pd2);
                m1[p] = fminf(m1[p], pd2);
                m2[p] = fminf(m2[p], hi);
                float tsel = c1 ? l1[p] : ld2;     // c1 => old l1 demotes to 2nd
                l2[p] = c2 ? tsel : l2[p];
                l1[p] = c1 ? ld2 : l1[p];
                lmin[p] = fminf(lmin[p], ld2);
                dl = fminf(dl, ld2);
            }
            float got = __shfl(dl, (lane - i) & 63, 64);
            gmin = fminf(gmin, got);
            kk = (kk + 1) & 63;
        }

        #pragma unroll
        for (int p = 0; p < P; ++p) {
            float mind = sqrtf(fmaxf(m1[p], 0.f));
            bool pm = mind < DIST_THRESH;
            float tgtv = fminf(mind, 2.0f * DIST_THRESH);
            float diff = f0[p] - tgtv;
            float ad = fabsf(diff);
            float sl1 = (ad < 1.0f) ? 0.5f * diff * diff : (ad - 0.5f);
            if (vp[p]) dist_acc += sl1;
            if (pm) {                               // pm false for dummy points
                p2g_acc += fmaxf(lmin[p], 0.f);
                sep_acc += sqrtf(fmaxf(l1[p], 0.f)) / sqrtf(fmaxf(l2[p], 1e-30f));
            }
        }
    }

    // ---- block-level reduction ----
    float v0 = dist_acc, v1 = p2g_acc, v2 = sep_acc;
    #pragma unroll
    for (int o = 32; o > 0; o >>= 1) {
        v0 += __shfl_down(v0, o, 64);
        v1 += __shfl_down(v1, o, 64);
        v2 += __shfl_down(v2, o, 64);
    }
    if (lane == 0) { rs[0][wib] = v0; rs[1][wib] = v1; rs[2][wib] = v2; }
    gredw[wib][lane] = gmin;
    __syncthreads();

    if (tid < 3) {
        float s = rs[tid][0] + rs[tid][1] + rs[tid][2] + rs[tid][3];
        atomicAdd(&sums[tid * B + b], s);
    }
    if (tid < KT) {
        float g = fminf(fminf(gredw[0][tid], gredw[1][tid]),
                        fminf(gredw[2][tid], gredw[3][tid]));
        g = fmaxf(g, 0.f);   // keep uint-ordered atomicMin valid
        atomicMin(&g2p_ws[b * KT + tid], __float_as_uint(g));
    }

    // ---- ticket: last block finalizes ----
    if (tid == 0) {
        __threadfence();
        unsigned int t = atomicAdd(ticket, 1u);
        is_last = (t == (unsigned int)(gridDim.x - 1));
    }
    __syncthreads();
    if (!is_last) return;

    {
        const int fb = tid >> 6, fk = tid & 63;
        float g = 0.f, nv = 0.f;
        if (fb < B) {
            int f = tF[fb * KT + fk];
            bool valid = false;
            for (int c = 0; c < n_classes; ++c) valid = valid || (f == classes[c]);
            if (valid) {
                nv = 1.f;
                // atomic read (device-coherent): min with 0xFFFFFFFF is a no-op write
                g = __uint_as_float(atomicMin(&g2p_ws[fb * KT + fk], 0xFFFFFFFFu));
            }
        }
        #pragma unroll
        for (int o = 32; o > 0; o >>= 1) {
            g  += __shfl_down(g, o, 64);
            nv += __shfl_down(nv, o, 64);
        }
        if (fb < B && fk == 0) {
            float sd = atomicAdd(&sums[0 * B + fb], 0.f);   // atomic reads
            float sp = atomicAdd(&sums[1 * B + fb], 0.f);
            float ss = atomicAdd(&sums[2 * B + fb], 0.f);
            float sep = (nv >= 2.f) ? ss : 0.f;
            lossb[fb] = W_DIST * sd + W_CHAMFER * (sp + g) + W_SEP * sep;
        }
        __syncthreads();
        if (tid == 0) {
            float s = 0.f;
            for (int i = 0; i < B; ++i) s += lossb[i];
            out[0] = s / (float)B;
        }
    }
}

extern "C" void kernel_launch(void* const* d_in, const int* in_sizes, int n_in,
                              void* d_out, int out_size, void* d_ws, size_t ws_size,
                              hipStream_t stream)
{
    const float* C       = (const float*)d_in[0];   // (B,N,3)
    const float* F       = (const float*)d_in[1];   // (B,N,4)
    const float* tC      = (const float*)d_in[2];   // (B,K,3)
    const int*   tF      = (const int*)d_in[3];     // (B,K)
    const int*   classes = (const int*)d_in[4];     // (6,)
    const int n_classes = in_sizes[4];
    const int B = 4;
    const int N = in_sizes[0] / (3 * B);            // 200000

    unsigned int* g2p_ws = (unsigned int*)d_ws;                 // 256 u32
    float*        sums   = (float*)((char*)d_ws + KT * B * 4);  // 12 f32
    unsigned int* ticket = (unsigned int*)((char*)d_ws + KT * B * 4 + 12 * 4);

    // g2p init: 0x7F7F7F7F == 3.39e38f, > any real value, uint-order == float-order
    hipMemsetAsync(g2p_ws, 0x7F, KT * B * sizeof(unsigned int), stream);
    hipMemsetAsync(sums, 0, 16 * sizeof(float), stream);        // sums + ticket + pad

    const int cpb = (N + 64 * P - 1) / (64 * P);    // 782 chunks per batch
    const int bpb = (cpb + 3) / 4;                  // 196 blocks/batch -> 1 chunk/wave
    landmark_fused<<<bpb * B, 256, 0, stream>>>(C, F, tC, tF, classes, n_classes,
                                                B, N, bpb, cpb, g2p_ws, sums, ticket,
                                                (float*)d_out);
}